// Round 4
// baseline (1081.458 us; speedup 1.0000x reference)
//
#include <hip/hip_runtime.h>
#include <hip/hip_bf16.h>
#include <stdint.h>

#define T_TOK 4096
#define H_DIM 1024
#define F_DIM 4096
#define NE 8

typedef float    f32x4  __attribute__((ext_vector_type(4)));
typedef __bf16   bf16x8 __attribute__((ext_vector_type(8)));
typedef uint16_t u16x8  __attribute__((ext_vector_type(8)));

#define AS1 __attribute__((address_space(1)))
#define AS3 __attribute__((address_space(3)))

__device__ __forceinline__ uint16_t f2bf(float f) {
  return __builtin_bit_cast(uint16_t, __float2bfloat16(f));
}

__device__ __forceinline__ void gld16(const void* g, void* l) {
  __builtin_amdgcn_global_load_lds((const AS1 void*)g, (AS3 void*)l, 16, 0, 0);
}

// ---------------- router: logits (fp32, exact), top-2 gates, compaction, x->bf16
__global__ __launch_bounds__(256) void router_k(
    const float* __restrict__ x, const float* __restrict__ wr,
    float* __restrict__ logits, uint16_t* __restrict__ xb,
    int* __restrict__ pairTok, float* __restrict__ pairGate,
    int* __restrict__ cnt)
{
  const int lane = threadIdx.x & 63;
  const int wid  = threadIdx.x >> 6;
  const int t    = blockIdx.x * 4 + wid;

  const float* xp = x + (size_t)t * H_DIM + lane * 16;
  f32x4 xv[4];
#pragma unroll
  for (int i = 0; i < 4; ++i) xv[i] = *(const f32x4*)(xp + 4 * i);

  u16x8 o0, o1;
#pragma unroll
  for (int j = 0; j < 4; ++j) {
    o0[j] = f2bf(xv[0][j]); o0[j + 4] = f2bf(xv[1][j]);
    o1[j] = f2bf(xv[2][j]); o1[j + 4] = f2bf(xv[3][j]);
  }
  uint16_t* xbp = xb + (size_t)t * H_DIM + lane * 16;
  *(u16x8*)xbp       = o0;
  *(u16x8*)(xbp + 8) = o1;

  float s[NE];
#pragma unroll
  for (int e = 0; e < NE; ++e) {
    const float* wp = wr + e * H_DIM + lane * 16;
    float acc = 0.f;
#pragma unroll
    for (int i = 0; i < 4; ++i) {
      f32x4 wv = *(const f32x4*)(wp + 4 * i);
#pragma unroll
      for (int j = 0; j < 4; ++j) acc += xv[i][j] * wv[j];
    }
#pragma unroll
    for (int off = 32; off > 0; off >>= 1) acc += __shfl_xor(acc, off, 64);
    s[e] = acc;
  }

  if (lane == 0) {
#pragma unroll
    for (int e = 0; e < NE; ++e) logits[t * NE + e] = s[e];
    int e1 = 0;
#pragma unroll
    for (int e = 1; e < NE; ++e) if (s[e] > s[e1]) e1 = e;
    int e2 = (e1 == 0) ? 1 : 0;
#pragma unroll
    for (int e = 0; e < NE; ++e)
      if (e != e1 && e != e2 && s[e] > s[e2]) e2 = e;
    const float d  = s[e2] - s[e1];              // <= 0
    const float g1 = 1.f / (1.f + __expf(d));
    const float g2 = 1.f - g1;
    int i1 = atomicAdd(cnt + e1, 1);
    pairTok[e1 * T_TOK + i1] = t;  pairGate[e1 * T_TOK + i1] = g1;
    int i2 = atomicAdd(cnt + e2, 1);
    pairTok[e2 * T_TOK + i2] = t;  pairGate[e2 * T_TOK + i2] = g2;
  }
}

__global__ void prefix_k(const int* __restrict__ cnt, int* __restrict__ base) {
  if (threadIdx.x == 0) {
    int b = 0;
#pragma unroll
    for (int e = 0; e < NE; ++e) { base[e] = b; b += cnt[e]; }
  }
}

// ---------------- stage 1: h = silu(x@w1^T) * (x@w3^T)
// NO-LDS direct-fragment kernel. Block tile M=256 x N=32, 4 waves (2M x 2N),
// wave tile 128M x 16N, dual-B. Every operand fragment is loaded straight from
// global in MFMA layout (16 rows x 64-128B contiguous per instruction).
// No barriers anywhere; register ping-pong prefetch; K offsets are immediates.
__global__ __launch_bounds__(256, 2) void ffn1_k(
    const uint16_t* __restrict__ xb, const float* __restrict__ w1,
    const float* __restrict__ w3, uint16_t* __restrict__ hbuf,
    const int* __restrict__ pairTok, const int* __restrict__ cnt,
    const int* __restrict__ base)
{
  const int e    = blockIdx.z;
  const int cnte = cnt[e];
  const int m0   = blockIdx.y * 256;
  if (m0 >= cnte) return;
  const int n0   = blockIdx.x * 32;
  const int lane = threadIdx.x & 63;
  const int wid  = threadIdx.x >> 6;
  const int wm   = (wid >> 1) * 128;   // 0 or 128
  const int wn   = (wid & 1) * 16;     // 0 or 16
  const int kg8  = (lane >> 4) * 8;    // k-subgroup offset (elements)

  // per-lane A row pointers (token gather is free here)
  const uint16_t* aptr[8];
#pragma unroll
  for (int i = 0; i < 8; ++i) {
    int ar = m0 + wm + i * 16 + (lane & 15);
    if (ar >= cnte) ar = cnte - 1;
    const int tok = pairTok[e * T_TOK + ar];
    aptr[i] = xb + (size_t)tok * H_DIM + kg8;
  }
  const int   nrow = n0 + wn + (lane & 15);
  const float* b1p = w1 + (size_t)e * F_DIM * H_DIM + (size_t)nrow * H_DIM + kg8;
  const float* b3p = w3 + (size_t)e * F_DIM * H_DIM + (size_t)nrow * H_DIM + kg8;

  const f32x4 fz = {0.f, 0.f, 0.f, 0.f};
  f32x4 acc1[8], acc3[8];
#pragma unroll
  for (int i = 0; i < 8; ++i) { acc1[i] = fz; acc3[i] = fz; }

#define LOAD_A(dst, kk)                                                   \
  _Pragma("unroll") for (int i = 0; i < 8; ++i)                           \
      dst[i] = *(const bf16x8*)(aptr[i] + (kk) * 32);

#define LOAD_B(d1, d3, kk)                                                \
  d1##0 = *(const f32x4*)(b1p + (kk) * 32);                               \
  d1##1 = *(const f32x4*)(b1p + (kk) * 32 + 4);                           \
  d3##0 = *(const f32x4*)(b3p + (kk) * 32);                               \
  d3##1 = *(const f32x4*)(b3p + (kk) * 32 + 4);

#define TILE(aset, r1, r3)                                                \
  {                                                                       \
    u16x8 u1, u3;                                                         \
    _Pragma("unroll") for (int j = 0; j < 4; ++j) {                       \
      u1[j] = f2bf(r1##0[j]); u1[j + 4] = f2bf(r1##1[j]);                 \
      u3[j] = f2bf(r3##0[j]); u3[j + 4] = f2bf(r3##1[j]);                 \
    }                                                                     \
    const bf16x8 b1f = __builtin_bit_cast(bf16x8, u1);                    \
    const bf16x8 b3f = __builtin_bit_cast(bf16x8, u3);                    \
    _Pragma("unroll") for (int i = 0; i < 8; ++i) {                       \
      acc1[i] = __builtin_amdgcn_mfma_f32_16x16x32_bf16(aset[i], b1f, acc1[i], 0, 0, 0); \
      acc3[i] = __builtin_amdgcn_mfma_f32_16x16x32_bf16(aset[i], b3f, acc3[i], 0, 0, 0); \
    }                                                                     \
  }

  bf16x8 aA[8], aB[8];
  f32x4 r1A0, r1A1, r3A0, r3A1;
  f32x4 r1B0, r1B1, r3B0, r3B1;

  LOAD_A(aA, 0)
  LOAD_B(r1A, r3A, 0)

#pragma unroll
  for (int tt = 0; tt < 16; ++tt) {
    const int t = tt * 2;
    LOAD_A(aB, t + 1)
    LOAD_B(r1B, r3B, t + 1)
    TILE(aA, r1A, r3A)
    if (t + 2 < 32) {
      LOAD_A(aA, t + 2)
      LOAD_B(r1A, r3A, t + 2)
    }
    TILE(aB, r1B, r3B)
  }
#undef LOAD_A
#undef LOAD_B
#undef TILE

  // epilogue: h = silu(a1) * a3 -> bf16. C/D: col=lane&15(n), row=(lane>>4)*4+r
  const int be  = base[e];
  const int col = n0 + wn + (lane & 15);
#pragma unroll
  for (int i = 0; i < 8; ++i) {
#pragma unroll
    for (int r = 0; r < 4; ++r) {
      const int lrow = m0 + wm + i * 16 + (lane >> 4) * 4 + r;
      if (lrow < cnte) {
        const float a  = acc1[i][r];
        const float hv = (a / (1.f + __expf(-a))) * acc3[i][r];
        hbuf[(size_t)(be + lrow) * F_DIM + col] = f2bf(hv);
      }
    }
  }
}

// ---------------- stage 2: out[t] += gate * (h @ w2^T)  (R1-proven structure)
__global__ __launch_bounds__(256, 2) void ffn2_k(
    const uint16_t* __restrict__ hbuf, const float* __restrict__ w2,
    float* __restrict__ out, const int* __restrict__ pairTok,
    const float* __restrict__ pairGate, const int* __restrict__ cnt,
    const int* __restrict__ base)
{
  const int e    = blockIdx.z;
  const int cnte = cnt[e];
  const int m0   = blockIdx.y * 128;
  if (m0 >= cnte) return;
  const int n0   = blockIdx.x * 128;
  const int tid  = threadIdx.x;
  const int lane = tid & 63;
  const int wid  = tid >> 6;
  const int wm   = (wid >> 1) * 64;
  const int wn   = (wid & 1) * 64;

  __shared__ __align__(16) uint16_t lsA[128 * 64];
  __shared__ __align__(16) uint16_t lsB[128 * 64];

  const int be = base[e];
  const float* w2e = w2 + (size_t)e * H_DIM * F_DIM;

  const uint16_t* asrc[4];
  const float*    bsrc[4];
#pragma unroll
  for (int q = 0; q < 4; ++q) {
    const int c = q * 256 + tid;
    const int row = c >> 3, pos = c & 7;
    const int kc  = pos ^ (row & 7);
    int rr = m0 + row; if (rr >= cnte) rr = cnte - 1;
    asrc[q] = hbuf + (size_t)(be + rr) * F_DIM + kc * 8;
    bsrc[q] = w2e + (size_t)(n0 + row) * F_DIM + kc * 8;
  }

  const f32x4 fz = {0.f, 0.f, 0.f, 0.f};
  f32x4 acc[4][4];
#pragma unroll
  for (int i = 0; i < 4; ++i)
#pragma unroll
    for (int j = 0; j < 4; ++j) acc[i][j] = fz;

  for (int kt = 0; kt < F_DIM; kt += 64) {
    __syncthreads();
#pragma unroll
    for (int q = 0; q < 4; ++q) {
      const int c = q * 256 + tid;
      gld16(asrc[q] + kt, &lsA[c * 8]);
    }
#pragma unroll
    for (int q = 0; q < 4; ++q) {
      const int c = q * 256 + tid;
      const float* sb = bsrc[q] + kt;
      f32x4 b0 = *(const f32x4*)sb;
      f32x4 b1 = *(const f32x4*)(sb + 4);
      u16x8 ob;
#pragma unroll
      for (int j = 0; j < 4; ++j) { ob[j] = f2bf(b0[j]); ob[j + 4] = f2bf(b1[j]); }
      *(u16x8*)&lsB[c * 8] = ob;
    }
    __syncthreads();
#pragma unroll
    for (int ks = 0; ks < 2; ++ks) {
      bf16x8 af[4], bf[4];
      const int kg = ks * 4 + (lane >> 4);
#pragma unroll
      for (int i = 0; i < 4; ++i) {
        const int ar = wm + i * 16 + (lane & 15);
        af[i] = *(const bf16x8*)&lsA[ar * 64 + ((kg ^ (ar & 7)) * 8)];
        const int br = wn + i * 16 + (lane & 15);
        bf[i] = *(const bf16x8*)&lsB[br * 64 + ((kg ^ (br & 7)) * 8)];
      }
#pragma unroll
      for (int i = 0; i < 4; ++i)
#pragma unroll
        for (int j = 0; j < 4; ++j)
          acc[i][j] = __builtin_amdgcn_mfma_f32_16x16x32_bf16(af[i], bf[j], acc[i][j], 0, 0, 0);
    }
  }

#pragma unroll
  for (int i = 0; i < 4; ++i) {
#pragma unroll
    for (int r = 0; r < 4; ++r) {
      const int lrow = m0 + wm + i * 16 + (lane >> 4) * 4 + r;
      if (lrow < cnte) {
        const int   t = pairTok [e * T_TOK + lrow];
        const float g = pairGate[e * T_TOK + lrow];
        float* op = out + (size_t)t * H_DIM + n0 + wn + (lane & 15);
#pragma unroll
        for (int j = 0; j < 4; ++j)
          unsafeAtomicAdd(op + j * 16, g * acc[i][j][r]);
      }
    }
  }
}

extern "C" void kernel_launch(void* const* d_in, const int* in_sizes, int n_in,
                              void* d_out, int out_size, void* d_ws, size_t ws_size,
                              hipStream_t stream)
{
  const float* x  = (const float*)d_in[0];
  const float* wr = (const float*)d_in[1];
  const float* w1 = (const float*)d_in[2];
  const float* w2 = (const float*)d_in[3];
  const float* w3 = (const float*)d_in[4];
  float* out    = (float*)d_out;
  float* logits = out + (size_t)T_TOK * H_DIM;

  uint8_t* ws = (uint8_t*)d_ws;
  const size_t XB_OFF   = 0;                                        // bf16 x   [T][H]   8 MB
  const size_t HB_OFF   = XB_OFF + (size_t)T_TOK * H_DIM * 2;       // bf16 h   [2T][F] 64 MB
  const size_t PT_OFF   = HB_OFF + (size_t)2 * T_TOK * F_DIM * 2;
  const size_t PG_OFF   = PT_OFF + (size_t)NE * T_TOK * 4;
  const size_t CNT_OFF  = PG_OFF + (size_t)NE * T_TOK * 4;
  const size_t BASE_OFF = CNT_OFF + 64;
  const size_t NEED     = BASE_OFF + 64;
  if (ws_size < NEED) return;

  uint16_t* xb      = (uint16_t*)(ws + XB_OFF);
  uint16_t* hb      = (uint16_t*)(ws + HB_OFF);
  int*      pairTok = (int*)(ws + PT_OFF);
  float*    pairGate= (float*)(ws + PG_OFF);
  int*      cnt     = (int*)(ws + CNT_OFF);
  int*      basep   = (int*)(ws + BASE_OFF);

  hipMemsetAsync(out, 0, (size_t)T_TOK * H_DIM * sizeof(float), stream);
  hipMemsetAsync(cnt, 0, 64, stream);
  router_k<<<T_TOK / 4, 256, 0, stream>>>(x, wr, logits, xb, pairTok, pairGate, cnt);
  prefix_k<<<1, 64, 0, stream>>>(cnt, basep);
  ffn1_k<<<dim3(F_DIM / 32, T_TOK / 256, NE), 256, 0, stream>>>(xb, w1, w3, hb, pairTok, cnt, basep);
  ffn2_k<<<dim3(H_DIM / 128, T_TOK / 128, NE), 256, 0, stream>>>(hb, w2, out, pairTok, pairGate, cnt, basep);
}

// Round 5
// 481.929 us; speedup vs baseline: 2.2440x; 2.2440x over previous
//
#include <hip/hip_runtime.h>
#include <hip/hip_bf16.h>
#include <stdint.h>

#define T_TOK 4096
#define H_DIM 1024
#define F_DIM 4096
#define NE 8

typedef float    f32x4  __attribute__((ext_vector_type(4)));
typedef __bf16   bf16x8 __attribute__((ext_vector_type(8)));
typedef uint16_t u16x8  __attribute__((ext_vector_type(8)));

#define AS1 __attribute__((address_space(1)))
#define AS3 __attribute__((address_space(3)))

__device__ __forceinline__ uint16_t f2bf(float f) {
  return __builtin_bit_cast(uint16_t, __float2bfloat16(f));
}

__device__ __forceinline__ void gld16(const void* g, void* l) {
  __builtin_amdgcn_global_load_lds((const AS1 void*)g, (AS3 void*)l, 16, 0, 0);
}

// ---------------- router: logits (fp32, exact), top-2 gates, compaction, x->bf16
__global__ __launch_bounds__(256) void router_k(
    const float* __restrict__ x, const float* __restrict__ wr,
    float* __restrict__ logits, uint16_t* __restrict__ xb,
    int* __restrict__ pairTok, float* __restrict__ pairGate,
    int* __restrict__ cnt)
{
  const int lane = threadIdx.x & 63;
  const int wid  = threadIdx.x >> 6;
  const int t    = blockIdx.x * 4 + wid;

  const float* xp = x + (size_t)t * H_DIM + lane * 16;
  f32x4 xv[4];
#pragma unroll
  for (int i = 0; i < 4; ++i) xv[i] = *(const f32x4*)(xp + 4 * i);

  u16x8 o0, o1;
#pragma unroll
  for (int j = 0; j < 4; ++j) {
    o0[j] = f2bf(xv[0][j]); o0[j + 4] = f2bf(xv[1][j]);
    o1[j] = f2bf(xv[2][j]); o1[j + 4] = f2bf(xv[3][j]);
  }
  uint16_t* xbp = xb + (size_t)t * H_DIM + lane * 16;
  *(u16x8*)xbp       = o0;
  *(u16x8*)(xbp + 8) = o1;

  float s[NE];
#pragma unroll
  for (int e = 0; e < NE; ++e) {
    const float* wp = wr + e * H_DIM + lane * 16;
    float acc = 0.f;
#pragma unroll
    for (int i = 0; i < 4; ++i) {
      f32x4 wv = *(const f32x4*)(wp + 4 * i);
#pragma unroll
      for (int j = 0; j < 4; ++j) acc += xv[i][j] * wv[j];
    }
#pragma unroll
    for (int off = 32; off > 0; off >>= 1) acc += __shfl_xor(acc, off, 64);
    s[e] = acc;
  }

  if (lane == 0) {
#pragma unroll
    for (int e = 0; e < NE; ++e) logits[t * NE + e] = s[e];
    int e1 = 0;
#pragma unroll
    for (int e = 1; e < NE; ++e) if (s[e] > s[e1]) e1 = e;
    int e2 = (e1 == 0) ? 1 : 0;
#pragma unroll
    for (int e = 0; e < NE; ++e)
      if (e != e1 && e != e2 && s[e] > s[e2]) e2 = e;
    const float d  = s[e2] - s[e1];              // <= 0
    const float g1 = 1.f / (1.f + __expf(d));
    const float g2 = 1.f - g1;
    int i1 = atomicAdd(cnt + e1, 1);
    pairTok[e1 * T_TOK + i1] = t;  pairGate[e1 * T_TOK + i1] = g1;
    int i2 = atomicAdd(cnt + e2, 1);
    pairTok[e2 * T_TOK + i2] = t;  pairGate[e2 * T_TOK + i2] = g2;
  }
}

__global__ void prefix_k(const int* __restrict__ cnt, int* __restrict__ base) {
  if (threadIdx.x == 0) {
    int b = 0;
#pragma unroll
    for (int e = 0; e < NE; ++e) { base[e] = b; b += cnt[e]; }
  }
}

// ---------------- stage 1: h = silu(x@w1^T) * (x@w3^T)
// R1-proven inner loop (BK=64, XOR swizzle, gld16-A, reg-staged fp32 B),
// regridded to BM=256 x BN=64 to halve fp32-weight L3 re-reads.
// 4 waves, wave tile 128M x 32N, dual acc = 128 f32/thread. LDS 48 KB.
__global__ __launch_bounds__(256, 2) void ffn1_k(
    const uint16_t* __restrict__ xb, const float* __restrict__ w1,
    const float* __restrict__ w3, uint16_t* __restrict__ hbuf,
    const int* __restrict__ pairTok, const int* __restrict__ cnt,
    const int* __restrict__ base)
{
  const int e    = blockIdx.z;
  const int cnte = cnt[e];
  const int m0   = blockIdx.y * 256;
  if (m0 >= cnte) return;
  const int n0   = blockIdx.x * 64;
  const int tid  = threadIdx.x;
  const int lane = tid & 63;
  const int wid  = tid >> 6;
  const int wm   = (wid >> 1) * 128;   // 0 or 128
  const int wn   = (wid & 1) * 32;     // 0 or 32

  __shared__ __align__(16) uint16_t lsA [256 * 64];  // 32 KB
  __shared__ __align__(16) uint16_t lsB1[ 64 * 64];  //  8 KB
  __shared__ __align__(16) uint16_t lsB3[ 64 * 64];  //  8 KB

  const float* w1e = w1 + (size_t)e * F_DIM * H_DIM;
  const float* w3e = w3 + (size_t)e * F_DIM * H_DIM;

  // A: 2048 16B-chunks, 8/thread. Linear chunk c holds logical k-chunk
  // kc = (c&7)^(row&7) (pre-swizzled source, LDS stays linear).
  const uint16_t* asrc[8];
#pragma unroll
  for (int q = 0; q < 8; ++q) {
    const int c = q * 256 + tid;
    const int row = c >> 3, pos = c & 7;
    const int kc  = pos ^ (row & 7);
    int ar = m0 + row; if (ar >= cnte) ar = cnte - 1;
    const int tok = pairTok[e * T_TOK + ar];
    asrc[q] = xb + (size_t)tok * H_DIM + kc * 8;
  }
  // B: 512 chunks each, 2/thread, fp32 source reg-staged.
  const float* b1src[2];
  const float* b3src[2];
  int bdst[2];
#pragma unroll
  for (int q = 0; q < 2; ++q) {
    const int c = q * 256 + tid;
    const int row = c >> 3, pos = c & 7;
    const int kc  = pos ^ (row & 7);
    bdst[q] = c * 8;
    b1src[q] = w1e + (size_t)(n0 + row) * H_DIM + kc * 8;
    b3src[q] = w3e + (size_t)(n0 + row) * H_DIM + kc * 8;
  }

  const f32x4 fz = {0.f, 0.f, 0.f, 0.f};
  f32x4 acc1[8][2], acc3[8][2];
#pragma unroll
  for (int i = 0; i < 8; ++i)
#pragma unroll
    for (int j = 0; j < 2; ++j) { acc1[i][j] = fz; acc3[i][j] = fz; }

  for (int kt = 0; kt < H_DIM; kt += 64) {
    __syncthreads();
#pragma unroll
    for (int q = 0; q < 8; ++q)
      gld16(asrc[q] + kt, &lsA[(q * 256 + tid) * 8]);
#pragma unroll
    for (int q = 0; q < 2; ++q) {
      const float* s1 = b1src[q] + kt;
      const float* s3 = b3src[q] + kt;
      f32x4 a0 = *(const f32x4*)s1;
      f32x4 a1 = *(const f32x4*)(s1 + 4);
      f32x4 c0 = *(const f32x4*)s3;
      f32x4 c1 = *(const f32x4*)(s3 + 4);
      u16x8 ob1, ob3;
#pragma unroll
      for (int j = 0; j < 4; ++j) {
        ob1[j] = f2bf(a0[j]); ob1[j + 4] = f2bf(a1[j]);
        ob3[j] = f2bf(c0[j]); ob3[j + 4] = f2bf(c1[j]);
      }
      *(u16x8*)&lsB1[bdst[q]] = ob1;
      *(u16x8*)&lsB3[bdst[q]] = ob3;
    }
    __syncthreads();
#pragma unroll
    for (int ks = 0; ks < 2; ++ks) {
      const int kg = ks * 4 + (lane >> 4);
      bf16x8 af[8], b1f[2], b3f[2];
#pragma unroll
      for (int i = 0; i < 8; ++i) {
        const int ar = wm + i * 16 + (lane & 15);
        af[i] = *(const bf16x8*)&lsA[ar * 64 + ((kg ^ (ar & 7)) * 8)];
      }
#pragma unroll
      for (int j = 0; j < 2; ++j) {
        const int br = wn + j * 16 + (lane & 15);
        b1f[j] = *(const bf16x8*)&lsB1[br * 64 + ((kg ^ (br & 7)) * 8)];
        b3f[j] = *(const bf16x8*)&lsB3[br * 64 + ((kg ^ (br & 7)) * 8)];
      }
#pragma unroll
      for (int i = 0; i < 8; ++i)
#pragma unroll
        for (int j = 0; j < 2; ++j) {
          acc1[i][j] = __builtin_amdgcn_mfma_f32_16x16x32_bf16(af[i], b1f[j], acc1[i][j], 0, 0, 0);
          acc3[i][j] = __builtin_amdgcn_mfma_f32_16x16x32_bf16(af[i], b3f[j], acc3[i][j], 0, 0, 0);
        }
    }
  }

  // epilogue: h = silu(a1)*a3 -> bf16. C/D: col=lane&15, row=(lane>>4)*4+r
  const int be = base[e];
#pragma unroll
  for (int i = 0; i < 8; ++i) {
#pragma unroll
    for (int r = 0; r < 4; ++r) {
      const int lrow = m0 + wm + i * 16 + (lane >> 4) * 4 + r;
      if (lrow < cnte) {
        uint16_t* hp = hbuf + (size_t)(be + lrow) * F_DIM + n0 + wn + (lane & 15);
#pragma unroll
        for (int j = 0; j < 2; ++j) {
          const float a  = acc1[i][j][r];
          const float hv = (a / (1.f + __expf(-a))) * acc3[i][j][r];
          hp[j * 16] = f2bf(hv);
        }
      }
    }
  }
}

// ---------------- stage 2: out[t] += gate * (h @ w2^T)
// Regridded to BM=256 x BN=128 (single acc), same proven inner loop. LDS 48 KB.
__global__ __launch_bounds__(256, 2) void ffn2_k(
    const uint16_t* __restrict__ hbuf, const float* __restrict__ w2,
    float* __restrict__ out, const int* __restrict__ pairTok,
    const float* __restrict__ pairGate, const int* __restrict__ cnt,
    const int* __restrict__ base)
{
  const int e    = blockIdx.z;
  const int cnte = cnt[e];
  const int m0   = blockIdx.y * 256;
  if (m0 >= cnte) return;
  const int n0   = blockIdx.x * 128;
  const int tid  = threadIdx.x;
  const int lane = tid & 63;
  const int wid  = tid >> 6;
  const int wm   = (wid >> 1) * 128;   // 0 or 128
  const int wn   = (wid & 1) * 64;     // 0 or 64

  __shared__ __align__(16) uint16_t lsA[256 * 64];   // 32 KB
  __shared__ __align__(16) uint16_t lsB[128 * 64];   // 16 KB

  const int be = base[e];
  const float* w2e = w2 + (size_t)e * H_DIM * F_DIM;

  const uint16_t* asrc[8];
#pragma unroll
  for (int q = 0; q < 8; ++q) {
    const int c = q * 256 + tid;
    const int row = c >> 3, pos = c & 7;
    const int kc  = pos ^ (row & 7);
    int rr = m0 + row; if (rr >= cnte) rr = cnte - 1;
    asrc[q] = hbuf + (size_t)(be + rr) * F_DIM + kc * 8;
  }
  const float* bsrc[4];
  int bdst[4];
#pragma unroll
  for (int q = 0; q < 4; ++q) {
    const int c = q * 256 + tid;
    const int row = c >> 3, pos = c & 7;
    const int kc  = pos ^ (row & 7);
    bdst[q] = c * 8;
    bsrc[q] = w2e + (size_t)(n0 + row) * F_DIM + kc * 8;
  }

  const f32x4 fz = {0.f, 0.f, 0.f, 0.f};
  f32x4 acc[8][4];
#pragma unroll
  for (int i = 0; i < 8; ++i)
#pragma unroll
    for (int j = 0; j < 4; ++j) acc[i][j] = fz;

  for (int kt = 0; kt < F_DIM; kt += 64) {
    __syncthreads();
#pragma unroll
    for (int q = 0; q < 8; ++q)
      gld16(asrc[q] + kt, &lsA[(q * 256 + tid) * 8]);
#pragma unroll
    for (int q = 0; q < 4; ++q) {
      const float* sb = bsrc[q] + kt;
      f32x4 b0 = *(const f32x4*)sb;
      f32x4 b1 = *(const f32x4*)(sb + 4);
      u16x8 ob;
#pragma unroll
      for (int j = 0; j < 4; ++j) { ob[j] = f2bf(b0[j]); ob[j + 4] = f2bf(b1[j]); }
      *(u16x8*)&lsB[bdst[q]] = ob;
    }
    __syncthreads();
#pragma unroll
    for (int ks = 0; ks < 2; ++ks) {
      const int kg = ks * 4 + (lane >> 4);
      bf16x8 af[8], bf[4];
#pragma unroll
      for (int i = 0; i < 8; ++i) {
        const int ar = wm + i * 16 + (lane & 15);
        af[i] = *(const bf16x8*)&lsA[ar * 64 + ((kg ^ (ar & 7)) * 8)];
      }
#pragma unroll
      for (int j = 0; j < 4; ++j) {
        const int br = wn + j * 16 + (lane & 15);
        bf[j] = *(const bf16x8*)&lsB[br * 64 + ((kg ^ (br & 7)) * 8)];
      }
#pragma unroll
      for (int i = 0; i < 8; ++i)
#pragma unroll
        for (int j = 0; j < 4; ++j)
          acc[i][j] = __builtin_amdgcn_mfma_f32_16x16x32_bf16(af[i], bf[j], acc[i][j], 0, 0, 0);
    }
  }

  // epilogue: gate-scale and accumulate into out (2 experts/token -> atomics)
#pragma unroll
  for (int i = 0; i < 8; ++i) {
#pragma unroll
    for (int r = 0; r < 4; ++r) {
      const int lrow = m0 + wm + i * 16 + (lane >> 4) * 4 + r;
      if (lrow < cnte) {
        const int   t = pairTok [e * T_TOK + lrow];
        const float g = pairGate[e * T_TOK + lrow];
        float* op = out + (size_t)t * H_DIM + n0 + wn + (lane & 15);
#pragma unroll
        for (int j = 0; j < 4; ++j)
          unsafeAtomicAdd(op + j * 16, g * acc[i][j][r]);
      }
    }
  }
}

extern "C" void kernel_launch(void* const* d_in, const int* in_sizes, int n_in,
                              void* d_out, int out_size, void* d_ws, size_t ws_size,
                              hipStream_t stream)
{
  const float* x  = (const float*)d_in[0];
  const float* wr = (const float*)d_in[1];
  const float* w1 = (const float*)d_in[2];
  const float* w2 = (const float*)d_in[3];
  const float* w3 = (const float*)d_in[4];
  float* out    = (float*)d_out;
  float* logits = out + (size_t)T_TOK * H_DIM;

  uint8_t* ws = (uint8_t*)d_ws;
  const size_t XB_OFF   = 0;                                        // bf16 x   [T][H]   8 MB
  const size_t HB_OFF   = XB_OFF + (size_t)T_TOK * H_DIM * 2;       // bf16 h   [2T][F] 64 MB
  const size_t PT_OFF   = HB_OFF + (size_t)2 * T_TOK * F_DIM * 2;
  const size_t PG_OFF   = PT_OFF + (size_t)NE * T_TOK * 4;
  const size_t CNT_OFF  = PG_OFF + (size_t)NE * T_TOK * 4;
  const size_t BASE_OFF = CNT_OFF + 64;
  const size_t NEED     = BASE_OFF + 64;
  if (ws_size < NEED) return;

  uint16_t* xb      = (uint16_t*)(ws + XB_OFF);
  uint16_t* hb      = (uint16_t*)(ws + HB_OFF);
  int*      pairTok = (int*)(ws + PT_OFF);
  float*    pairGate= (float*)(ws + PG_OFF);
  int*      cnt     = (int*)(ws + CNT_OFF);
  int*      basep   = (int*)(ws + BASE_OFF);

  hipMemsetAsync(out, 0, (size_t)T_TOK * H_DIM * sizeof(float), stream);
  hipMemsetAsync(cnt, 0, 64, stream);
  router_k<<<T_TOK / 4, 256, 0, stream>>>(x, wr, logits, xb, pairTok, pairGate, cnt);
  prefix_k<<<1, 64, 0, stream>>>(cnt, basep);
  // grid.y covers worst-case cnte (up to T_TOK); blocks beyond cnte exit early
  ffn1_k<<<dim3(F_DIM / 64, T_TOK / 256, NE), 256, 0, stream>>>(xb, w1, w3, hb, pairTok, cnt, basep);
  ffn2_k<<<dim3(H_DIM / 128, T_TOK / 256, NE), 256, 0, stream>>>(hb, w2, out, pairTok, pairGate, cnt, basep);
}